// Round 1
// baseline (1445.079 us; speedup 1.0000x reference)
//
#include <hip/hip_runtime.h>
#include <math.h>

#define NDIR 5
#define E_ 16
#define W_ 3
#define D_ 128
#define P_ 256
#define B_ 4
#define PTILE 64

struct RoutesArg { int r[E_][W_]; };

// Replicates the Python _cantor_coord + stable argsort route construction.
// Done on host in double precision (Python float == IEEE double), coords cast
// to float like np.float32, distances in float, stable insertion sort.
static RoutesArg make_routes() {
    float coords[E_];
    for (int i = 0; i < E_; ++i) {
        double x = (double)i / (double)(E_ - 1);
        if (x < 1e-6) x = 1e-6;
        if (x > 1.0 - 1e-6) x = 1.0 - 1e-6;
        double val = 0.0, factor = 0.5;
        for (int d = 0; d < 8; ++d) {
            x *= 3.0;
            int digit = (int)x;    // trunc == floor for x>=0, matches int(x)
            x -= (double)digit;
            if (digit == 2) val += factor;
            factor *= 0.5;
        }
        coords[i] = (float)val;
    }
    RoutesArg R;
    for (int i = 0; i < E_; ++i) {
        float d[E_]; int idx[E_];
        for (int j = 0; j < E_; ++j) { d[j] = fabsf(coords[j] - coords[i]); idx[j] = j; }
        // stable insertion sort (strict > shift keeps equal keys in index order,
        // matching np.argsort(kind='stable'))
        for (int a = 1; a < E_; ++a) {
            int key = idx[a]; float kd = d[key];
            int c = a - 1;
            while (c >= 0 && d[idx[c]] > kd) { idx[c + 1] = idx[c]; --c; }
            idx[c + 1] = key;
        }
        int top[W_] = { idx[0], idx[1], idx[2] };
        // np.sort of the W chosen indices (ascending)
        if (top[0] > top[1]) { int t = top[0]; top[0] = top[1]; top[1] = t; }
        if (top[1] > top[2]) { int t = top[1]; top[1] = top[2]; top[2] = t; }
        if (top[0] > top[1]) { int t = top[0]; top[0] = top[1]; top[1] = t; }
        for (int w = 0; w < W_; ++w) R.r[i][w] = top[w];
    }
    return R;
}

// Block = (e, b, p-tile of 64). 256 threads = 4 waves.
// wave  = one 32-wide feature quarter of D=128
// lane  = one query p within the tile
// Loops x = 0..NDIR-1, accumulating softmax(q*s) @ V weighted by fusion wts.
__global__ __launch_bounds__(256) void cantor_attn_kernel(
    const float* __restrict__ Q, const float* __restrict__ K,
    const float* __restrict__ V, const float* __restrict__ betas,
    const float* __restrict__ temperature, const float* __restrict__ fusion,
    float* __restrict__ out, RoutesArg routes)
{
    __shared__ float s_lds[W_ * P_];
    __shared__ float red_max[4], red_min[4];

    const int tid  = threadIdx.x;
    const int lane = tid & 63;
    const int wv   = tid >> 6;            // wave id -> feature quarter
    const int bid  = blockIdx.x;
    const int pt   = bid & 3;
    const int b    = (bid >> 2) & 3;
    const int e    = bid >> 4;

    const int p  = pt * PTILE + lane;     // query this lane owns
    const int f0 = wv * 32;               // feature quarter base

    const float temp = fabsf(temperature[0]) + 1e-6f;

    // fusion softmax (5 elems, every thread computes)
    float fw[NDIR];
    float fmx = -1e30f;
    for (int i = 0; i < NDIR; ++i) { fw[i] = fusion[i]; fmx = fmaxf(fmx, fw[i]); }
    float fsum = 0.f;
    for (int i = 0; i < NDIR; ++i) { fw[i] = __expf(fw[i] - fmx); fsum += fw[i]; }
    for (int i = 0; i < NDIR; ++i) fw[i] /= fsum;

    // routes + beta factors for this e
    int   rt[W_];
    float bf[W_];
    #pragma unroll
    for (int w = 0; w < W_; ++w) {
        rt[w] = routes.r[e][w];
        float bv = betas[e * E_ + rt[w]];
        bf[w] = (rt[w] == e) ? 1.0f : 1.0f / (1.0f + __expf(-bv));
    }

    float4 acc[8];
    #pragma unroll
    for (int u = 0; u < 8; ++u) acc[u] = make_float4(0.f, 0.f, 0.f, 0.f);

    for (int x = 0; x < NDIR; ++x) {
        // ---- stage s = K*beta into LDS; track min/max ----
        float lmax = -1e30f, lmin = 1e30f;
        {
            const int k = tid;            // 256 threads cover k
            #pragma unroll
            for (int w = 0; w < W_; ++w) {
                float kv = K[(((size_t)x * E_ + rt[w]) * B_ + b) * P_ + k];
                float sv = kv * bf[w];
                s_lds[w * P_ + k] = sv;
                lmax = fmaxf(lmax, sv);
                lmin = fminf(lmin, sv);
            }
        }
        #pragma unroll
        for (int off = 32; off; off >>= 1) {
            lmax = fmaxf(lmax, __shfl_xor(lmax, off));
            lmin = fminf(lmin, __shfl_xor(lmin, off));
        }
        if (lane == 0) { red_max[wv] = lmax; red_min[wv] = lmin; }
        __syncthreads();
        const float smax = fmaxf(fmaxf(red_max[0], red_max[1]), fmaxf(red_max[2], red_max[3]));
        const float smin = fminf(fminf(red_min[0], red_min[1]), fminf(red_min[2], red_min[3]));

        const float q  = Q[(((size_t)x * E_ + e) * B_ + b) * P_ + p];
        const float qs = q / temp;
        const float m  = (qs >= 0.f) ? qs * smax : qs * smin;  // exact row max

        float denom = 0.f;
        float4 tmp[8];
        #pragma unroll
        for (int u = 0; u < 8; ++u) tmp[u] = make_float4(0.f, 0.f, 0.f, 0.f);

        for (int w = 0; w < W_; ++w) {
            const float4* __restrict__ Vp = reinterpret_cast<const float4*>(
                V + ((((size_t)x * E_ + rt[w]) * B_ + b) * (size_t)P_) * D_ + f0);
            for (int k = 0; k < P_; ++k) {
                const float a = __expf(qs * s_lds[w * P_ + k] - m);
                denom += a;
                const float4* vp = Vp + (size_t)k * (D_ / 4);
                #pragma unroll
                for (int u = 0; u < 8; ++u) {
                    float4 v = vp[u];
                    tmp[u].x += a * v.x; tmp[u].y += a * v.y;
                    tmp[u].z += a * v.z; tmp[u].w += a * v.w;
                }
            }
        }
        const float scale = fw[x] / denom;
        #pragma unroll
        for (int u = 0; u < 8; ++u) {
            acc[u].x += scale * tmp[u].x; acc[u].y += scale * tmp[u].y;
            acc[u].z += scale * tmp[u].z; acc[u].w += scale * tmp[u].w;
        }
        __syncthreads();   // protect s_lds before next x overwrites it
    }

    // out[b, e*P + p, f0..f0+31]
    float4* __restrict__ op = reinterpret_cast<float4*>(
        out + ((size_t)b * (E_ * P_) + (size_t)e * P_ + p) * D_ + f0);
    #pragma unroll
    for (int u = 0; u < 8; ++u) op[u] = acc[u];
}

extern "C" void kernel_launch(void* const* d_in, const int* in_sizes, int n_in,
                              void* d_out, int out_size, void* d_ws, size_t ws_size,
                              hipStream_t stream) {
    (void)in_sizes; (void)n_in; (void)d_ws; (void)ws_size; (void)out_size;
    RoutesArg R = make_routes();
    const float* Q     = (const float*)d_in[0];
    const float* K     = (const float*)d_in[1];
    const float* V     = (const float*)d_in[2];
    const float* betas = (const float*)d_in[3];
    const float* tempr = (const float*)d_in[4];
    const float* fuse  = (const float*)d_in[5];
    float* out = (float*)d_out;

    dim3 grid(E_ * B_ * (P_ / PTILE));   // 256 blocks
    dim3 block(256);
    hipLaunchKernelGGL(cantor_attn_kernel, grid, block, 0, stream,
                       Q, K, V, betas, tempr, fuse, out, R);
}

// Round 2
// 81.285 us; speedup vs baseline: 17.7779x; 17.7779x over previous
//
#include <hip/hip_runtime.h>
#include <math.h>

#define NDIR 5
#define E_ 16
#define W_ 3
#define D_ 128
#define P_ 256
#define B_ 4
#define PQ_TILE 64
#define KSTEP 32

typedef __attribute__((ext_vector_type(8))) short short8;
typedef __attribute__((ext_vector_type(4))) float f32x4;

struct RoutesArg { int r[E_][W_]; };

// Replicates Python _cantor_coord + stable argsort route construction on host.
static RoutesArg make_routes() {
    float coords[E_];
    for (int i = 0; i < E_; ++i) {
        double x = (double)i / (double)(E_ - 1);
        if (x < 1e-6) x = 1e-6;
        if (x > 1.0 - 1e-6) x = 1.0 - 1e-6;
        double val = 0.0, factor = 0.5;
        for (int d = 0; d < 8; ++d) {
            x *= 3.0;
            int digit = (int)x;
            x -= (double)digit;
            if (digit == 2) val += factor;
            factor *= 0.5;
        }
        coords[i] = (float)val;
    }
    RoutesArg R;
    for (int i = 0; i < E_; ++i) {
        float d[E_]; int idx[E_];
        for (int j = 0; j < E_; ++j) { d[j] = fabsf(coords[j] - coords[i]); idx[j] = j; }
        for (int a = 1; a < E_; ++a) {
            int key = idx[a]; float kd = d[key];
            int c = a - 1;
            while (c >= 0 && d[idx[c]] > kd) { idx[c + 1] = idx[c]; --c; }
            idx[c + 1] = key;
        }
        int top[W_] = { idx[0], idx[1], idx[2] };
        if (top[0] > top[1]) { int t = top[0]; top[0] = top[1]; top[1] = t; }
        if (top[1] > top[2]) { int t = top[1]; top[1] = top[2]; top[2] = t; }
        if (top[0] > top[1]) { int t = top[0]; top[0] = top[1]; top[1] = t; }
        for (int w = 0; w < W_; ++w) R.r[i][w] = top[w];
    }
    return R;
}

// exact RNE float->bf16 (finite inputs only)
static __device__ __forceinline__ unsigned short f2bf(float f) {
    union { float f; unsigned int u; } v; v.f = f;
    unsigned int r = (v.u + 0x7FFFu + ((v.u >> 16) & 1u)) >> 16;
    return (unsigned short)r;
}

// Block = (e, b, pq). 256 threads = 4 waves, wave = f-quarter (32 cols).
// Per x: A[64p x 768k] = exp(qs_p * s_k) generated once into LDS (bf16,
// swizzled, double-buffered), V fragments loaded direct from global,
// C[64 x 128] accumulated via mfma_f32_16x16x32_bf16, scaled by fw[x]/den.
__global__ __launch_bounds__(256) void cantor_mfma_kernel(
    const float* __restrict__ Q, const float* __restrict__ K,
    const float* __restrict__ V, const float* __restrict__ betas,
    const float* __restrict__ temperature, const float* __restrict__ fusion,
    float* __restrict__ out, RoutesArg routes)
{
    __shared__ float s_lds[W_ * P_];                      // 3 KB
    __shared__ unsigned short a_lds[2][PQ_TILE * KSTEP];  // 2 x 4 KB
    __shared__ float den_lds[PQ_TILE * 4];                // 1 KB
    __shared__ float scale_lds[PQ_TILE];                  // 256 B

    const int tid  = threadIdx.x;
    const int lane = tid & 63;
    const int wv   = tid >> 6;
    const int bid  = blockIdx.x;
    const int pq   = bid & 3;
    const int b    = (bid >> 2) & 3;
    const int e    = bid >> 4;

    const int f0  = wv * 32;
    const int l15 = lane & 15;
    const int lg  = lane >> 4;     // k-octet group for fragments
    const int gp  = tid >> 2;      // A-gen: p row within tile (0..63)
    const int gg  = tid & 3;       // A-gen: k-octet (0..3)

    const float temp = fabsf(temperature[0]) + 1e-6f;

    // fusion softmax
    float fw[NDIR];
    float fmx = -1e30f;
    #pragma unroll
    for (int i = 0; i < NDIR; ++i) { fw[i] = fusion[i]; fmx = fmaxf(fmx, fw[i]); }
    float fsum = 0.f;
    #pragma unroll
    for (int i = 0; i < NDIR; ++i) { fw[i] = __expf(fw[i] - fmx); fsum += fw[i]; }
    #pragma unroll
    for (int i = 0; i < NDIR; ++i) fw[i] /= fsum;

    int   rt[W_];
    float bf3[W_];
    #pragma unroll
    for (int w = 0; w < W_; ++w) {
        rt[w] = routes.r[e][w];
        float bv = betas[e * E_ + rt[w]];
        bf3[w] = (rt[w] == e) ? 1.0f : 1.0f / (1.0f + __expf(-bv));
    }

    // LDS addressing (ushort element offsets), XOR-swizzled 16B slots
    const int a_wr_off = gp * 32 + ((gg ^ (gp & 3)) * 8);
    const int swz      = lg ^ (l15 & 3);

    f32x4 outacc[4][2];
    #pragma unroll
    for (int fr = 0; fr < 4; ++fr)
        #pragma unroll
        for (int c = 0; c < 2; ++c)
            outacc[fr][c] = (f32x4){0.f, 0.f, 0.f, 0.f};

    for (int x = 0; x < NDIR; ++x) {
        // stage s = K * beta (768 floats)
        #pragma unroll
        for (int w = 0; w < W_; ++w)
            s_lds[w * P_ + tid] =
                K[(((size_t)(x * E_ + rt[w])) * B_ + b) * P_ + tid] * bf3[w];

        const float qs =
            Q[(((size_t)(x * E_ + e)) * B_ + b) * P_ + pq * PQ_TILE + gp] / temp;

        f32x4 acc[4][2];
        #pragma unroll
        for (int fr = 0; fr < 4; ++fr)
            #pragma unroll
            for (int c = 0; c < 2; ++c)
                acc[fr][c] = (f32x4){0.f, 0.f, 0.f, 0.f};
        float den = 0.f;

        __syncthreads();   // s_lds ready

        #pragma unroll
        for (int w = 0; w < W_; ++w) {
            const float* __restrict__ Vw =
                V + ((((size_t)(x * E_ + rt[w])) * B_ + b) * (size_t)P_) * D_ + f0;
            #pragma unroll
            for (int k8 = 0; k8 < 8; ++k8) {
                const int kb  = w * 8 + k8;       // 0..23
                const int cur = kb & 1;

                // ---- issue B-fragment loads (latency hidden under exp gen) ----
                float bv[2][8];
                {
                    const float* vp = Vw + (size_t)(k8 * KSTEP + 8 * lg) * D_ + l15;
                    #pragma unroll
                    for (int c = 0; c < 2; ++c)
                        #pragma unroll
                        for (int i = 0; i < 8; ++i)
                            bv[c][i] = vp[(size_t)i * D_ + c * 16];
                }

                // ---- generate A tile (8 exps per thread) into LDS ----
                {
                    const float4* sp =
                        reinterpret_cast<const float4*>(s_lds) + kb * 8 + gg * 2;
                    const float4 s0 = sp[0], s1 = sp[1];
                    float a0 = __expf(qs * s0.x), a1 = __expf(qs * s0.y);
                    float a2 = __expf(qs * s0.z), a3 = __expf(qs * s0.w);
                    float a4 = __expf(qs * s1.x), a5 = __expf(qs * s1.y);
                    float a6 = __expf(qs * s1.z), a7 = __expf(qs * s1.w);
                    den += ((a0 + a1) + (a2 + a3)) + ((a4 + a5) + (a6 + a7));
                    short8 av;
                    av[0] = (short)f2bf(a0); av[1] = (short)f2bf(a1);
                    av[2] = (short)f2bf(a2); av[3] = (short)f2bf(a3);
                    av[4] = (short)f2bf(a4); av[5] = (short)f2bf(a5);
                    av[6] = (short)f2bf(a6); av[7] = (short)f2bf(a7);
                    *reinterpret_cast<short8*>(&a_lds[cur][a_wr_off]) = av;
                }

                __syncthreads();   // A tile ready (also drains B loads)

                // ---- convert B to bf16 fragments ----
                short8 bfrag[2];
                #pragma unroll
                for (int c = 0; c < 2; ++c) {
                    short8 t;
                    #pragma unroll
                    for (int i = 0; i < 8; ++i) t[i] = (short)f2bf(bv[c][i]);
                    bfrag[c] = t;
                }

                // ---- read A fragments + MFMA ----
                #pragma unroll
                for (int fr = 0; fr < 4; ++fr) {
                    const short8 af = *reinterpret_cast<const short8*>(
                        &a_lds[cur][(fr * 16 + l15) * 32 + swz * 8]);
                    acc[fr][0] = __builtin_amdgcn_mfma_f32_16x16x32_bf16(
                        af, bfrag[0], acc[fr][0], 0, 0, 0);
                    acc[fr][1] = __builtin_amdgcn_mfma_f32_16x16x32_bf16(
                        af, bfrag[1], acc[fr][1], 0, 0, 0);
                }
            }
        }

        // ---- denominator reduce + scale accumulate ----
        den_lds[tid] = den;        // layout [gp][gg] == tid
        __syncthreads();
        if (tid < PQ_TILE) {
            float d = den_lds[tid * 4] + den_lds[tid * 4 + 1] +
                      den_lds[tid * 4 + 2] + den_lds[tid * 4 + 3];
            scale_lds[tid] = fw[x] / d;
        }
        __syncthreads();

        #pragma unroll
        for (int fr = 0; fr < 4; ++fr)
            #pragma unroll
            for (int r = 0; r < 4; ++r) {
                const float sc = scale_lds[fr * 16 + 4 * lg + r];
                outacc[fr][0][r] += sc * acc[fr][0][r];
                outacc[fr][1][r] += sc * acc[fr][1][r];
            }
        __syncthreads();   // protect scale_lds/den_lds before next x
    }

    // ---- store: out[b][e*256 + pq*64 + prow][f0 + c*16 + l15] ----
    const size_t outbase =
        ((size_t)b * (E_ * P_) + (size_t)e * P_ + pq * PQ_TILE) * D_ + f0;
    #pragma unroll
    for (int fr = 0; fr < 4; ++fr)
        #pragma unroll
        for (int r = 0; r < 4; ++r) {
            const int prow = fr * 16 + 4 * lg + r;
            float* op = out + outbase + (size_t)prow * D_;
            op[l15]      = outacc[fr][0][r];
            op[16 + l15] = outacc[fr][1][r];
        }
}

extern "C" void kernel_launch(void* const* d_in, const int* in_sizes, int n_in,
                              void* d_out, int out_size, void* d_ws, size_t ws_size,
                              hipStream_t stream) {
    (void)in_sizes; (void)n_in; (void)d_ws; (void)ws_size; (void)out_size;
    RoutesArg R = make_routes();
    const float* Q     = (const float*)d_in[0];
    const float* K     = (const float*)d_in[1];
    const float* V     = (const float*)d_in[2];
    const float* betas = (const float*)d_in[3];
    const float* tempr = (const float*)d_in[4];
    const float* fuse  = (const float*)d_in[5];
    float* out = (float*)d_out;

    dim3 grid(E_ * B_ * (P_ / PQ_TILE));   // 256 blocks
    dim3 block(256);
    hipLaunchKernelGGL(cantor_mfma_kernel, grid, block, 0, stream,
                       Q, K, V, betas, tempr, fuse, out, R);
}

// Round 5
// 79.296 us; speedup vs baseline: 18.2238x; 1.0251x over previous
//
#include <hip/hip_runtime.h>
#include <math.h>

#define NDIR 5
#define E_ 16
#define W_ 3
#define D_ 128
#define P_ 256
#define B_ 4
#define ROWS 64
#define NPQ 4

typedef __attribute__((ext_vector_type(8))) short short8;
typedef __attribute__((ext_vector_type(4))) float f32x4;

struct RoutesArg { int r[E_][W_]; };

// Replicates Python _cantor_coord + stable argsort route construction on host.
static RoutesArg make_routes() {
    float coords[E_];
    for (int i = 0; i < E_; ++i) {
        double x = (double)i / (double)(E_ - 1);
        if (x < 1e-6) x = 1e-6;
        if (x > 1.0 - 1e-6) x = 1.0 - 1e-6;
        double val = 0.0, factor = 0.5;
        for (int d = 0; d < 8; ++d) {
            x *= 3.0;
            int digit = (int)x;
            x -= (double)digit;
            if (digit == 2) val += factor;
            factor *= 0.5;
        }
        coords[i] = (float)val;
    }
    RoutesArg R;
    for (int i = 0; i < E_; ++i) {
        float d[E_]; int idx[E_];
        for (int j = 0; j < E_; ++j) { d[j] = fabsf(coords[j] - coords[i]); idx[j] = j; }
        for (int a = 1; a < E_; ++a) {
            int key = idx[a]; float kd = d[key];
            int c = a - 1;
            while (c >= 0 && d[idx[c]] > kd) { idx[c + 1] = idx[c]; --c; }
            idx[c + 1] = key;
        }
        int top[W_] = { idx[0], idx[1], idx[2] };
        if (top[0] > top[1]) { int t = top[0]; top[0] = top[1]; top[1] = t; }
        if (top[1] > top[2]) { int t = top[1]; top[1] = top[2]; top[2] = t; }
        if (top[0] > top[1]) { int t = top[0]; top[0] = top[1]; top[1] = t; }
        for (int w = 0; w < W_; ++w) R.r[i][w] = top[w];
    }
    return R;
}

// exact RNE float->bf16 (finite inputs only) — proven in Round 2
static __device__ __forceinline__ unsigned short f2bf(float f) {
    union { float f; unsigned int u; } v; v.f = f;
    unsigned int r = (v.u + 0x7FFFu + ((v.u >> 16) & 1u)) >> 16;
    return (unsigned short)r;
}

static __device__ __forceinline__ short8 pack8(const float* a) {
    short8 s;
    #pragma unroll
    for (int i = 0; i < 8; ++i) s[i] = (short)f2bf(a[i]);
    return s;
}

// Block = (x, e, b, pq-tile of 64 rows). 256 threads = 4 waves, wave = f-quarter.
// A-fragments (exp(q*s) in bf16) are computed per-lane in registers -> no LDS
// A-tile, no k-loop barriers. Each block emits its x's scaled contribution.
template <bool ATOMIC>
__global__ __launch_bounds__(256) void cantor_partial_kernel(
    const float* __restrict__ Q, const float* __restrict__ K,
    const float* __restrict__ V, const float* __restrict__ betas,
    const float* __restrict__ temperature, const float* __restrict__ fusion,
    float* __restrict__ target, RoutesArg routes)
{
    __shared__ float s_lds[W_ * P_];   // 3 KB

    // XCD-bijective swizzle: 1280 blocks = 8 XCDs x 160
    const int orig = blockIdx.x;
    const int wg   = (orig & 7) * 160 + (orig >> 3);

    const int pq = wg & 3;
    const int b  = (wg >> 2) & 3;
    const int e  = (wg >> 4) & 15;
    const int x  = wg >> 8;

    const int tid  = threadIdx.x;
    const int lane = tid & 63;
    const int wv   = tid >> 6;
    const int f0   = wv * 32;
    const int l15  = lane & 15;
    const int lg   = lane >> 4;

    const float temp = fabsf(temperature[0]) + 1e-6f;

    // fusion softmax -> weight for this x
    float fwx;
    {
        float fv[NDIR], fmx = -1e30f, fsum = 0.f;
        #pragma unroll
        for (int i = 0; i < NDIR; ++i) { fv[i] = fusion[i]; fmx = fmaxf(fmx, fv[i]); }
        #pragma unroll
        for (int i = 0; i < NDIR; ++i) { fv[i] = __expf(fv[i] - fmx); fsum += fv[i]; }
        fwx = fv[x] / fsum;
    }

    int rt[W_]; float bf3[W_];
    #pragma unroll
    for (int w = 0; w < W_; ++w) {
        rt[w] = routes.r[e][w];
        float bv = betas[e * E_ + rt[w]];
        bf3[w] = (rt[w] == e) ? 1.0f : 1.0f / (1.0f + __expf(-bv));
    }

    // stage s = K * beta (768 floats)
    #pragma unroll
    for (int w = 0; w < W_; ++w)
        s_lds[w * P_ + tid] =
            K[(((size_t)(x * E_ + rt[w])) * B_ + b) * P_ + tid] * bf3[w];

    // q rows this lane contributes to (scaled by 1/temp; __expf handles log2e)
    const float* Qb = Q + (((size_t)(x * E_ + e)) * B_ + b) * P_ + pq * ROWS;
    float q4[4];
    #pragma unroll
    for (int fr = 0; fr < 4; ++fr)
        q4[fr] = Qb[fr * 16 + l15] / temp;

    __syncthreads();   // s_lds ready — the only barrier

    f32x4 acc[4][2];
    #pragma unroll
    for (int fr = 0; fr < 4; ++fr) {
        acc[fr][0] = (f32x4){0.f, 0.f, 0.f, 0.f};
        acc[fr][1] = (f32x4){0.f, 0.f, 0.f, 0.f};
    }
    float den[4] = {0.f, 0.f, 0.f, 0.f};

    #pragma unroll
    for (int w = 0; w < W_; ++w) {
        const float* __restrict__ Vw =
            V + (((size_t)(x * E_ + rt[w])) * B_ + b) * (size_t)(P_ * D_) + f0 + l15;
        const float* sb = s_lds + w * P_ + 8 * lg;
        #pragma unroll
        for (int k8 = 0; k8 < 8; ++k8) {
            // ---- issue B (V) loads early ----
            float bv0[8], bv1[8];
            const float* vp = Vw + (size_t)(k8 * 32 + 8 * lg) * D_;
            #pragma unroll
            for (int i = 0; i < 8; ++i) { bv0[i] = vp[i * D_]; bv1[i] = vp[i * D_ + 16]; }

            // ---- s octet for this lane group (broadcast reads) ----
            float sv[8];
            {
                const float4 s0_ = *reinterpret_cast<const float4*>(sb + k8 * 32);
                const float4 s1_ = *reinterpret_cast<const float4*>(sb + k8 * 32 + 4);
                sv[0] = s0_.x; sv[1] = s0_.y; sv[2] = s0_.z; sv[3] = s0_.w;
                sv[4] = s1_.x; sv[5] = s1_.y; sv[6] = s1_.z; sv[7] = s1_.w;
            }

            // ---- A fragments: 32 exps in registers (hides V latency) ----
            short8 af[4];
            #pragma unroll
            for (int fr = 0; fr < 4; ++fr) {
                float ev[8];
                #pragma unroll
                for (int i = 0; i < 8; ++i) ev[i] = __expf(q4[fr] * sv[i]);
                den[fr] += ((ev[0] + ev[1]) + (ev[2] + ev[3])) +
                           ((ev[4] + ev[5]) + (ev[6] + ev[7]));
                af[fr] = pack8(ev);
            }

            // ---- B fragments ----
            short8 bfr[2];
            bfr[0] = pack8(bv0);
            bfr[1] = pack8(bv1);

            // ---- 8 MFMAs ----
            #pragma unroll
            for (int fr = 0; fr < 4; ++fr) {
                acc[fr][0] = __builtin_amdgcn_mfma_f32_16x16x32_bf16(
                    af[fr], bfr[0], acc[fr][0], 0, 0, 0);
                acc[fr][1] = __builtin_amdgcn_mfma_f32_16x16x32_bf16(
                    af[fr], bfr[1], acc[fr][1], 0, 0, 0);
            }
        }
    }

    // ---- full-row denominators: sum across the 4 lane-groups ----
    #pragma unroll
    for (int fr = 0; fr < 4; ++fr) {
        den[fr] += __shfl_xor(den[fr], 16);
        den[fr] += __shfl_xor(den[fr], 32);
    }

    // ---- scale + write ----
    const size_t obase = ((((size_t)b * E_ + e) * NPQ) + pq) * (ROWS * D_);
    float* __restrict__ tgt = ATOMIC
        ? target
        : target + (size_t)x * ((size_t)B_ * E_ * NPQ * ROWS * D_);

    #pragma unroll
    for (int fr = 0; fr < 4; ++fr) {
        #pragma unroll
        for (int r = 0; r < 4; ++r) {
            const float dr = __shfl(den[fr], 4 * lg + r);   // den of row fr*16+4*lg+r
            const float sc = fwx / dr;
            const int row = fr * 16 + 4 * lg + r;
            float* op = tgt + obase + (size_t)row * D_ + f0;
            const float v0 = sc * acc[fr][0][r];
            const float v1 = sc * acc[fr][1][r];
            if (ATOMIC) {
                atomicAdd(op + l15, v0);          // safe CAS-based add (fallback only)
                atomicAdd(op + 16 + l15, v1);
            } else {
                op[l15]      = v0;
                op[16 + l15] = v1;
            }
        }
    }
}

__global__ __launch_bounds__(256) void reduce5_kernel(
    const float* __restrict__ part, float* __restrict__ out)
{
    const size_t i = (size_t)blockIdx.x * 256 + threadIdx.x;   // float4 index
    const float4* __restrict__ p = reinterpret_cast<const float4*>(part);
    float4 a = p[i];
    #pragma unroll
    for (int x = 1; x < NDIR; ++x) {
        float4 t = p[(size_t)x * 524288 + i];
        a.x += t.x; a.y += t.y; a.z += t.z; a.w += t.w;
    }
    reinterpret_cast<float4*>(out)[i] = a;
}

extern "C" void kernel_launch(void* const* d_in, const int* in_sizes, int n_in,
                              void* d_out, int out_size, void* d_ws, size_t ws_size,
                              hipStream_t stream) {
    (void)in_sizes; (void)n_in;
    RoutesArg R = make_routes();
    const float* Q     = (const float*)d_in[0];
    const float* K     = (const float*)d_in[1];
    const float* V     = (const float*)d_in[2];
    const float* betas = (const float*)d_in[3];
    const float* tempr = (const float*)d_in[4];
    const float* fuse  = (const float*)d_in[5];
    float* out = (float*)d_out;

    const size_t partial_bytes = (size_t)NDIR * B_ * E_ * NPQ * ROWS * D_ * 4;  // ~42 MB
    dim3 grid(NDIR * E_ * B_ * NPQ);   // 1280
    dim3 block(256);

    if (ws_size >= partial_bytes) {
        float* part = (float*)d_ws;
        hipLaunchKernelGGL((cantor_partial_kernel<false>), grid, block, 0, stream,
                           Q, K, V, betas, tempr, fuse, part, R);
        hipLaunchKernelGGL(reduce5_kernel, dim3(2048), block, 0, stream,
                           part, out);
    } else {
        (void)hipMemsetAsync(d_out, 0, (size_t)out_size * 4, stream);
        hipLaunchKernelGGL((cantor_partial_kernel<true>), grid, block, 0, stream,
                           Q, K, V, betas, tempr, fuse, out, R);
    }
}